// Round 8
// baseline (254.663 us; speedup 1.0000x reference)
//
#include <hip/hip_runtime.h>

#define NB 4
#define CH 512
#define NN 4096
#define DD 64
#define LOG2E 1.44269504088896f

typedef __attribute__((ext_vector_type(8))) short bf16x8;
typedef __attribute__((ext_vector_type(4))) float f32x4;

#define MFMA(a, b, c) __builtin_amdgcn_mfma_f32_16x16x32_bf16((a), (b), (c), 0, 0, 0)

__device__ inline unsigned short f2bf(float f) {
    unsigned int u = __builtin_bit_cast(unsigned int, f);
    unsigned int r = u + 0x7fffu + ((u >> 16) & 1u);
    return (unsigned short)(r >> 16);
}

__device__ inline unsigned short f2bf_trunc(float f) {
    return (unsigned short)(__builtin_bit_cast(unsigned int, f) >> 16);
}

__device__ inline float bf2f(unsigned short u) {
    return __builtin_bit_cast(float, ((unsigned int)u) << 16);
}

__device__ inline bf16x8 ld8(const unsigned short* p) {
    return *reinterpret_cast<const bf16x8*>(p);
}

// ---------------- kernel 0: convert weights fp32 -> bf16 ----------------
__global__ __launch_bounds__(256) void convert_w(
    const float* __restrict__ Wq, const float* __restrict__ Wk,
    const float* __restrict__ Wv, const float* __restrict__ Wo,
    unsigned short* __restrict__ oq, unsigned short* __restrict__ ok,
    unsigned short* __restrict__ ov, unsigned short* __restrict__ oo) {
    int i = blockIdx.x * 256 + threadIdx.x;  // 32768 elems each
    oq[i] = f2bf(Wq[i]);
    ok[i] = f2bf(Wk[i]);
    ov[i] = f2bf(Wv[i]);
    oo[i] = f2bf(Wo[i]);
}

// ---------------- kernel 1: QKV projection ----------------
// grid B*256: 16-row n-tile. Each wave owns output slice dt=w over the FULL
// C=512 loop -> no cross-wave reduction, one barrier total.
// Q is pre-scaled by log2(e) so attn softmax can use raw v_exp_f32.
__global__ __launch_bounds__(256) void qkv_kernel(
    const float* __restrict__ x,
    const unsigned short* __restrict__ Wq, const unsigned short* __restrict__ Wk,
    const unsigned short* __restrict__ Wv,
    const float* __restrict__ bq, const float* __restrict__ bk, const float* __restrict__ bv,
    unsigned short* __restrict__ Q, unsigned short* __restrict__ K,
    unsigned short* __restrict__ VT) {
    const int b = blockIdx.x >> 8;
    const int n0 = (blockIdx.x & 255) * 16;
    const int t = threadIdx.x;
    const int lane = t & 63, w = t >> 6;
    const int l15 = lane & 15, g = lane >> 4;

    __shared__ unsigned short sxT[16][520];  // [n][c]

    // stage full x-tile transposed: sxT[n][c] = x[b][c][n0+n]
    {
        const int cbase = t >> 2;
        const int nq = (t & 3) * 4;
#pragma unroll
        for (int p = 0; p < 8; ++p) {
            int c = p * 64 + cbase;
            float4 v = *reinterpret_cast<const float4*>(
                &x[((size_t)(b * CH + c)) * NN + n0 + nq]);
            sxT[nq + 0][c] = f2bf(v.x);
            sxT[nq + 1][c] = f2bf(v.y);
            sxT[nq + 2][c] = f2bf(v.z);
            sxT[nq + 3][c] = f2bf(v.w);
        }
    }
    __syncthreads();

    const int d = w * 16 + l15;  // this wave's W-row / output column
    f32x4 aQ = {0.f, 0.f, 0.f, 0.f}, aK = aQ, aV = aQ;
#pragma unroll
    for (int i = 0; i < 16; ++i) {
        int c = i * 32 + 8 * g;
        bf16x8 ax = ld8(&sxT[l15][c]);
        aQ = MFMA(ax, ld8(&Wq[d * CH + c]), aQ);
        aK = MFMA(ax, ld8(&Wk[d * CH + c]), aK);
        aV = MFMA(ld8(&Wv[d * CH + c]), ax, aV);
    }

    // Q/K: row n = n0+4g+r, col d; Q scaled by log2e for exp2-domain softmax
    {
        float biasq = bq[d], biask = bk[d];
#pragma unroll
        for (int r = 0; r < 4; ++r) {
            int n = n0 + 4 * g + r;
            Q[((size_t)b * NN + n) * DD + d] = f2bf((aQ[r] + biasq) * LOG2E);
            K[((size_t)b * NN + n) * DD + d] = f2bf(aK[r] + biask);
        }
        // VT: row dv = w*16+4g+r, col n = n0+l15
#pragma unroll
        for (int r = 0; r < 4; ++r) {
            int dv = w * 16 + 4 * g + r;
            VT[((size_t)b * DD + dv) * NN + n0 + l15] = f2bf(aV[r] + bv[dv]);
        }
    }
}

// ---------------- kernel 2: flash attention, KV-split ----------------
// K/V are L1/L2-resident (1 MB/batch): fragments load DIRECTLY from global,
// no LDS staging, ZERO barriers in the KV loop -> waves run independently.
// sP stays wave-private LDS (in-wave ds ordering suffices).
__global__ __launch_bounds__(256) void attn_kernel(
    const unsigned short* __restrict__ Q, const unsigned short* __restrict__ K,
    const unsigned short* __restrict__ VT,
    unsigned short* __restrict__ PO, float* __restrict__ PML, int KVLEN) {
    const int s = blockIdx.x >> 8;
    const int bq_ = blockIdx.x & 255;
    const int b = bq_ >> 6;
    const int n0 = (bq_ & 63) * 64;
    const int t = threadIdx.x;
    const int lane = t & 63, w = t >> 6;
    const int l15 = lane & 15, g = lane >> 4;

    __shared__ unsigned short sP[4][16][76];  // per-wave [n][m]

    const int qrow = n0 + 16 * w + l15;
    bf16x8 qf0 = ld8(&Q[((size_t)b * NN + qrow) * DD + 0 + 8 * g]);
    bf16x8 qf1 = ld8(&Q[((size_t)b * NN + qrow) * DD + 32 + 8 * g]);

    f32x4 oacc[4];
    const f32x4 z = {0.f, 0.f, 0.f, 0.f};
#pragma unroll
    for (int i = 0; i < 4; ++i) oacc[i] = z;
    float m_run[4], l_part[4];  // m in log2 domain (Q pre-scaled)
#pragma unroll
    for (int r = 0; r < 4; ++r) { m_run[r] = -1e30f; l_part[r] = 0.f; }

    const int kv_begin = s * KVLEN;
    const int kv_end = kv_begin + KVLEN;

    for (int m0 = kv_begin; m0 < kv_end; m0 += 64) {
        const unsigned short* Kb_ = &K[((size_t)b * NN + m0) * DD];
        const unsigned short* Vb_ = &VT[(size_t)b * DD * NN + m0];

        // S' = (Q*log2e) K^T : 16 (n) x 64 (m) per wave, K from global
        f32x4 sv[4];
#pragma unroll
        for (int ct = 0; ct < 4; ++ct) sv[ct] = z;
#pragma unroll
        for (int ct = 0; ct < 4; ++ct) {
            bf16x8 kf0 = ld8(&Kb_[(ct * 16 + l15) * DD + 0 + 8 * g]);
            sv[ct] = MFMA(qf0, kf0, sv[ct]);
            bf16x8 kf1 = ld8(&Kb_[(ct * 16 + l15) * DD + 32 + 8 * g]);
            sv[ct] = MFMA(qf1, kf1, sv[ct]);
        }

        // defer-max online softmax (log2 domain)
        float ownmax[4];
        bool ok = true;
#pragma unroll
        for (int r = 0; r < 4; ++r) {
            ownmax[r] = fmaxf(fmaxf(sv[0][r], sv[1][r]), fmaxf(sv[2][r], sv[3][r]));
            ok = ok && (ownmax[r] <= m_run[r] + 8.f);
        }
        if (!__all(ok)) {
#pragma unroll
            for (int r = 0; r < 4; ++r) {
                float mx = ownmax[r];
#pragma unroll
                for (int d_ = 8; d_ >= 1; d_ >>= 1) mx = fmaxf(mx, __shfl_xor(mx, d_, 64));
                float mnew = fmaxf(m_run[r], mx);
                float c_ = __builtin_amdgcn_exp2f(m_run[r] - mnew);
                m_run[r] = mnew;
                l_part[r] *= c_;
#pragma unroll
                for (int dt = 0; dt < 4; ++dt) oacc[dt][r] *= c_;
            }
        }
#pragma unroll
        for (int r = 0; r < 4; ++r) {
            float p0 = __builtin_amdgcn_exp2f(sv[0][r] - m_run[r]);
            float p1 = __builtin_amdgcn_exp2f(sv[1][r] - m_run[r]);
            float p2 = __builtin_amdgcn_exp2f(sv[2][r] - m_run[r]);
            float p3 = __builtin_amdgcn_exp2f(sv[3][r] - m_run[r]);
            sv[0][r] = p0; sv[1][r] = p1; sv[2][r] = p2; sv[3][r] = p3;
            l_part[r] += (p0 + p1) + (p2 + p3);
        }

        // P -> LDS (truncating pack; wave-private, no barrier)
#pragma unroll
        for (int ct = 0; ct < 4; ++ct)
#pragma unroll
            for (int r = 0; r < 4; ++r)
                sP[w][4 * g + r][ct * 16 + l15] = f2bf_trunc(sv[ct][r]);

        // O += P V, V fragments straight from global (VT[d][m], m contiguous)
#pragma unroll
        for (int kk = 0; kk < 2; ++kk) {
            bf16x8 pf = ld8(&sP[w][l15][kk * 32 + 8 * g]);
#pragma unroll
            for (int dt = 0; dt < 4; ++dt) {
                bf16x8 vf = ld8(&Vb_[(size_t)(dt * 16 + l15) * NN + kk * 32 + 8 * g]);
                oacc[dt] = MFMA(pf, vf, oacc[dt]);
            }
        }
    }

    // epilogue: reduce deferred l across the 16-lane row group, store partials
#pragma unroll
    for (int r = 0; r < 4; ++r) {
        float lt = l_part[r];
#pragma unroll
        for (int d_ = 8; d_ >= 1; d_ >>= 1) lt += __shfl_xor(lt, d_, 64);
        int n = n0 + 16 * w + 4 * g + r;
        size_t rowidx = (size_t)s * NB * NN + (size_t)b * NN + n;
#pragma unroll
        for (int dt = 0; dt < 4; ++dt)
            PO[rowidx * DD + dt * 16 + l15] = f2bf(oacc[dt][r]);
        if (l15 == 0) {
            PML[rowidx * 2 + 0] = m_run[r];  // log2-domain
            PML[rowidx * 2 + 1] = lt;
        }
    }
}

// ---------------- kernel 3: combine + output projection + residual ----------------
__global__ __launch_bounds__(256) void out_fused(
    const unsigned short* __restrict__ Wo, const unsigned short* __restrict__ PO,
    const float* __restrict__ PML, const float* __restrict__ bo,
    const float* __restrict__ gamma, const float* __restrict__ x,
    float* __restrict__ out, int S) {
    const int bid = blockIdx.x;
    const int b = bid >> 8;
    const int rest = bid & 255;
    const int n0 = (rest >> 2) * 64;
    const int c0 = (rest & 3) * 128;
    const int t = threadIdx.x;
    const int lane = t & 63, w = t >> 6;
    const int l15 = lane & 15, g = lane >> 4;

    __shared__ unsigned short sATT[64][72];  // [n][d]

    // phase 1: combine KV-split partials for this n-tile (m's are log2-domain)
    {
        const int row = t >> 2;
        const int dq = (t & 3) * 16;
        const size_t base = (size_t)b * NN + n0 + row;
        float m = -1e30f;
        for (int s = 0; s < S; ++s)
            m = fmaxf(m, PML[((size_t)s * NB * NN + base) * 2]);
        float acc[16];
#pragma unroll
        for (int j = 0; j < 16; ++j) acc[j] = 0.f;
        float l = 0.f;
        for (int s = 0; s < S; ++s) {
            size_t rowidx = (size_t)s * NB * NN + base;
            float ms = PML[rowidx * 2 + 0];
            float ls = PML[rowidx * 2 + 1];
            float wgt = __builtin_amdgcn_exp2f(ms - m);
            l += wgt * ls;
            bf16x8 a0 = ld8(&PO[rowidx * DD + dq]);
            bf16x8 a1 = ld8(&PO[rowidx * DD + dq + 8]);
#pragma unroll
            for (int j = 0; j < 8; ++j) {
                acc[j] += wgt * bf2f((unsigned short)a0[j]);
                acc[8 + j] += wgt * bf2f((unsigned short)a1[j]);
            }
        }
        float inv = 1.f / l;
        bf16x8 o0, o1;
#pragma unroll
        for (int j = 0; j < 8; ++j) {
            o0[j] = (short)f2bf(acc[j] * inv);
            o1[j] = (short)f2bf(acc[8 + j] * inv);
        }
        *reinterpret_cast<bf16x8*>(&sATT[row][dq]) = o0;
        *reinterpret_cast<bf16x8*>(&sATT[row][dq + 8]) = o1;
    }
    __syncthreads();

    // phase 2: out[c, n] = gamma*(Wo . att + bo) + x
    const int cw = c0 + w * 32;
    f32x4 acc2[2][4];
    const f32x4 z = {0.f, 0.f, 0.f, 0.f};
#pragma unroll
    for (int i = 0; i < 2; ++i)
#pragma unroll
        for (int j = 0; j < 4; ++j) acc2[i][j] = z;

#pragma unroll
    for (int kk = 0; kk < 2; ++kk) {
        bf16x8 af[2], bfr[4];
#pragma unroll
        for (int ct = 0; ct < 2; ++ct)
            af[ct] = ld8(&Wo[(cw + ct * 16 + l15) * DD + kk * 32 + 8 * g]);
#pragma unroll
        for (int nt = 0; nt < 4; ++nt)
            bfr[nt] = ld8(&sATT[nt * 16 + l15][kk * 32 + 8 * g]);
#pragma unroll
        for (int ct = 0; ct < 2; ++ct)
#pragma unroll
            for (int nt = 0; nt < 4; ++nt) acc2[ct][nt] = MFMA(af[ct], bfr[nt], acc2[ct][nt]);
    }

    float gm = gamma[0];
#pragma unroll
    for (int ct = 0; ct < 2; ++ct) {
        int c = cw + ct * 16 + 4 * g;
#pragma unroll
        for (int r = 0; r < 4; ++r) {
            float bias = bo[c + r];
#pragma unroll
            for (int nt = 0; nt < 4; ++nt) {
                int n = n0 + nt * 16 + l15;
                size_t idx = ((size_t)b * CH + c + r) * NN + n;
                out[idx] = gm * (acc2[ct][nt][r] + bias) + x[idx];
            }
        }
    }
}

extern "C" void kernel_launch(void* const* d_in, const int* in_sizes, int n_in,
                              void* d_out, int out_size, void* d_ws, size_t ws_size,
                              hipStream_t stream) {
    const float* x = (const float*)d_in[0];
    const float* Wq = (const float*)d_in[1];
    const float* bq = (const float*)d_in[2];
    const float* Wk = (const float*)d_in[3];
    const float* bk = (const float*)d_in[4];
    const float* Wv = (const float*)d_in[5];
    const float* bv = (const float*)d_in[6];
    const float* Wo = (const float*)d_in[7];
    const float* bo = (const float*)d_in[8];
    const float* gamma = (const float*)d_in[9];
    float* out = (float*)d_out;

    char* ws = (char*)d_ws;
    unsigned short* Wq_bf = (unsigned short*)(ws + 0);
    unsigned short* Wk_bf = (unsigned short*)(ws + 65536);
    unsigned short* Wv_bf = (unsigned short*)(ws + 131072);
    unsigned short* Wo_bf = (unsigned short*)(ws + 196608);
    unsigned short* Qb = (unsigned short*)(ws + 262144);
    unsigned short* Kb = (unsigned short*)(ws + 262144 + 2097152);
    unsigned short* VTb = (unsigned short*)(ws + 262144 + 2 * 2097152);
    const size_t po_off = 262144 + 3ull * 2097152;

    // KV-split factor (deterministic: depends only on ws_size). S=8 measured
    // worse than S=4 (77.7 vs 69.4 us) -> S=4.
    int S = 4;
    while (S > 1 &&
           ws_size < po_off + (size_t)S * (2097152ull + 131072ull))
        S >>= 1;
    unsigned short* PO = (unsigned short*)(ws + po_off);
    float* PML = (float*)(ws + po_off + (size_t)S * 2097152ull);

    hipLaunchKernelGGL(convert_w, dim3(128), dim3(256), 0, stream,
                       Wq, Wk, Wv, Wo, Wq_bf, Wk_bf, Wv_bf, Wo_bf);
    hipLaunchKernelGGL(qkv_kernel, dim3(1024), dim3(256), 0, stream,
                       x, Wq_bf, Wk_bf, Wv_bf, bq, bk, bv, Qb, Kb, VTb);
    hipLaunchKernelGGL(attn_kernel, dim3(256 * S), dim3(256), 0, stream,
                       Qb, Kb, VTb, PO, PML, NN / S);
    hipLaunchKernelGGL(out_fused, dim3(1024), dim3(256), 0, stream,
                       Wo_bf, PO, PML, bo, gamma, x, out, S);
}

// Round 11
// 187.490 us; speedup vs baseline: 1.3583x; 1.3583x over previous
//
#include <hip/hip_runtime.h>

#define NB 4
#define CH 512
#define NN 4096
#define DD 64
#define LOG2E 1.44269504088896f

typedef __attribute__((ext_vector_type(8))) short bf16x8;
typedef __attribute__((ext_vector_type(4))) float f32x4;

#define MFMA(a, b, c) __builtin_amdgcn_mfma_f32_16x16x32_bf16((a), (b), (c), 0, 0, 0)

__device__ inline unsigned short f2bf(float f) {
    unsigned int u = __builtin_bit_cast(unsigned int, f);
    unsigned int r = u + 0x7fffu + ((u >> 16) & 1u);
    return (unsigned short)(r >> 16);
}

__device__ inline unsigned short f2bf_trunc(float f) {
    return (unsigned short)(__builtin_bit_cast(unsigned int, f) >> 16);
}

__device__ inline float bf2f(unsigned short u) {
    return __builtin_bit_cast(float, ((unsigned int)u) << 16);
}

__device__ inline bf16x8 ld8(const unsigned short* p) {
    return *reinterpret_cast<const bf16x8*>(p);
}

// swizzled LDS address for a [*][64]-bf16 tile: row stride 128B, byte-chunk
// XOR (row&7)<<4 spreads the 16-row column reads across 8 bank-quads (T2).
__device__ inline unsigned short* swzp(unsigned short* base, int row, int col) {
    return (unsigned short*)((char*)base + row * 128 + ((col * 2) ^ ((row & 7) << 4)));
}

// ---------------- kernel 0: convert weights fp32 -> bf16 ----------------
__global__ __launch_bounds__(256) void convert_w(
    const float* __restrict__ Wq, const float* __restrict__ Wk,
    const float* __restrict__ Wv, const float* __restrict__ Wo,
    unsigned short* __restrict__ oq, unsigned short* __restrict__ ok,
    unsigned short* __restrict__ ov, unsigned short* __restrict__ oo) {
    int i = blockIdx.x * 256 + threadIdx.x;  // 32768 elems each
    oq[i] = f2bf(Wq[i]);
    ok[i] = f2bf(Wk[i]);
    ov[i] = f2bf(Wv[i]);
    oo[i] = f2bf(Wo[i]);
}

// ---------------- kernel 1: QKV projection (unchanged, measured ~neutral) ----
__global__ __launch_bounds__(256) void qkv_kernel(
    const float* __restrict__ x,
    const unsigned short* __restrict__ Wq, const unsigned short* __restrict__ Wk,
    const unsigned short* __restrict__ Wv,
    const float* __restrict__ bq, const float* __restrict__ bk, const float* __restrict__ bv,
    unsigned short* __restrict__ Q, unsigned short* __restrict__ K,
    unsigned short* __restrict__ VT) {
    const int b = blockIdx.x >> 8;
    const int n0 = (blockIdx.x & 255) * 16;
    const int t = threadIdx.x;
    const int lane = t & 63, w = t >> 6;
    const int l15 = lane & 15, g = lane >> 4;

    __shared__ unsigned short sxT[16][520];  // [n][c]

    {
        const int cbase = t >> 2;
        const int nq = (t & 3) * 4;
#pragma unroll
        for (int p = 0; p < 8; ++p) {
            int c = p * 64 + cbase;
            float4 v = *reinterpret_cast<const float4*>(
                &x[((size_t)(b * CH + c)) * NN + n0 + nq]);
            sxT[nq + 0][c] = f2bf(v.x);
            sxT[nq + 1][c] = f2bf(v.y);
            sxT[nq + 2][c] = f2bf(v.z);
            sxT[nq + 3][c] = f2bf(v.w);
        }
    }
    __syncthreads();

    const int d = w * 16 + l15;
    f32x4 aQ = {0.f, 0.f, 0.f, 0.f}, aK = aQ, aV = aQ;
#pragma unroll
    for (int i = 0; i < 16; ++i) {
        int c = i * 32 + 8 * g;
        bf16x8 ax = ld8(&sxT[l15][c]);
        aQ = MFMA(ax, ld8(&Wq[d * CH + c]), aQ);
        aK = MFMA(ax, ld8(&Wk[d * CH + c]), aK);
        aV = MFMA(ld8(&Wv[d * CH + c]), ax, aV);
    }

    {
        float biasq = bq[d], biask = bk[d];
#pragma unroll
        for (int r = 0; r < 4; ++r) {
            int n = n0 + 4 * g + r;
            Q[((size_t)b * NN + n) * DD + d] = f2bf((aQ[r] + biasq) * LOG2E);
            K[((size_t)b * NN + n) * DD + d] = f2bf(aK[r] + biask);
        }
#pragma unroll
        for (int r = 0; r < 4; ++r) {
            int dv = w * 16 + 4 * g + r;
            VT[((size_t)b * DD + dv) * NN + n0 + l15] = f2bf(aV[r] + bv[dv]);
        }
    }
}

// ---------------- kernel 2: flash attention, KV-split ----------------
// LDS-staged (reuse across 4 waves) + DOUBLE BUFFER: issue t+1 loads, compute
// tile t, write t+1 to buf^1, ONE barrier. XOR-swizzled unpadded tiles keep
// LDS at exactly 40960 B -> 4 blocks/CU.
__global__ __launch_bounds__(256) void attn_kernel(
    const unsigned short* __restrict__ Q, const unsigned short* __restrict__ K,
    const unsigned short* __restrict__ VT,
    unsigned short* __restrict__ PO, float* __restrict__ PML, int KVLEN) {
    const int s = blockIdx.x >> 8;
    const int bq_ = blockIdx.x & 255;
    const int b = bq_ >> 6;
    const int n0 = (bq_ & 63) * 64;
    const int t = threadIdx.x;
    const int lane = t & 63, w = t >> 6;
    const int l15 = lane & 15, g = lane >> 4;

    __shared__ unsigned short sK[2][64][64];   // [buf][m][d], swizzled
    __shared__ unsigned short sVT[2][64][64];  // [buf][d][m], swizzled
    __shared__ unsigned short sP[4][16][64];   // per-wave [n][m], swizzled

    const int qrow = n0 + 16 * w + l15;
    bf16x8 qf0 = ld8(&Q[((size_t)b * NN + qrow) * DD + 0 + 8 * g]);
    bf16x8 qf1 = ld8(&Q[((size_t)b * NN + qrow) * DD + 32 + 8 * g]);

    f32x4 oacc[4];
    const f32x4 z = {0.f, 0.f, 0.f, 0.f};
#pragma unroll
    for (int i = 0; i < 4; ++i) oacc[i] = z;
    float m_run[4], l_part[4];  // log2 domain (Q pre-scaled)
#pragma unroll
    for (int r = 0; r < 4; ++r) { m_run[r] = -1e30f; l_part[r] = 0.f; }

    const int kv_begin = s * KVLEN;
    const int kv_end = kv_begin + KVLEN;
    const int srow = t >> 2, sc16 = (t & 3) * 16;
    unsigned short* sPw = &sP[w][0][0];

    // prologue: tile 0 -> regs -> buf 0
    bf16x8 pk0, pk1, pv0, pv1;
    {
        const unsigned short* kp = &K[((size_t)b * NN + kv_begin + srow) * DD + sc16];
        pk0 = ld8(kp); pk1 = ld8(kp + 8);
        const unsigned short* vp = &VT[((size_t)b * DD + srow) * NN + kv_begin + sc16];
        pv0 = ld8(vp); pv1 = ld8(vp + 8);
    }
    *reinterpret_cast<bf16x8*>(swzp(&sK[0][0][0], srow, sc16)) = pk0;
    *reinterpret_cast<bf16x8*>(swzp(&sK[0][0][0], srow, sc16 + 8)) = pk1;
    *reinterpret_cast<bf16x8*>(swzp(&sVT[0][0][0], srow, sc16)) = pv0;
    *reinterpret_cast<bf16x8*>(swzp(&sVT[0][0][0], srow, sc16 + 8)) = pv1;
    __syncthreads();

    int cur = 0;
    for (int m0 = kv_begin; m0 < kv_end; m0 += 64) {
        const bool more = (m0 + 64 < kv_end);
        // T14: issue next-tile loads NOW; they drain under this tile's compute
        if (more) {
            const unsigned short* kp = &K[((size_t)b * NN + m0 + 64 + srow) * DD + sc16];
            pk0 = ld8(kp); pk1 = ld8(kp + 8);
            const unsigned short* vp = &VT[((size_t)b * DD + srow) * NN + m0 + 64 + sc16];
            pv0 = ld8(vp); pv1 = ld8(vp + 8);
        }
        unsigned short* sKc = &sK[cur][0][0];
        unsigned short* sVc = &sVT[cur][0][0];

        // S' = (Q*log2e) K^T : 16 (n) x 64 (m) per wave
        f32x4 sv[4];
#pragma unroll
        for (int ct = 0; ct < 4; ++ct) sv[ct] = z;
#pragma unroll
        for (int ct = 0; ct < 4; ++ct) {
            bf16x8 kf0 = ld8(swzp(sKc, ct * 16 + l15, 8 * g));
            sv[ct] = MFMA(qf0, kf0, sv[ct]);
            bf16x8 kf1 = ld8(swzp(sKc, ct * 16 + l15, 32 + 8 * g));
            sv[ct] = MFMA(qf1, kf1, sv[ct]);
        }

        // defer-max online softmax (log2 domain)
        float ownmax[4];
        bool ok = true;
#pragma unroll
        for (int r = 0; r < 4; ++r) {
            ownmax[r] = fmaxf(fmaxf(sv[0][r], sv[1][r]), fmaxf(sv[2][r], sv[3][r]));
            ok = ok && (ownmax[r] <= m_run[r] + 8.f);
        }
        if (!__all(ok)) {
#pragma unroll
            for (int r = 0; r < 4; ++r) {
                float mx = ownmax[r];
#pragma unroll
                for (int d_ = 8; d_ >= 1; d_ >>= 1) mx = fmaxf(mx, __shfl_xor(mx, d_, 64));
                float mnew = fmaxf(m_run[r], mx);
                float c_ = __builtin_amdgcn_exp2f(m_run[r] - mnew);
                m_run[r] = mnew;
                l_part[r] *= c_;
#pragma unroll
                for (int dt = 0; dt < 4; ++dt) oacc[dt][r] *= c_;
            }
        }
#pragma unroll
        for (int r = 0; r < 4; ++r) {
            float p0 = __builtin_amdgcn_exp2f(sv[0][r] - m_run[r]);
            float p1 = __builtin_amdgcn_exp2f(sv[1][r] - m_run[r]);
            float p2 = __builtin_amdgcn_exp2f(sv[2][r] - m_run[r]);
            float p3 = __builtin_amdgcn_exp2f(sv[3][r] - m_run[r]);
            sv[0][r] = p0; sv[1][r] = p1; sv[2][r] = p2; sv[3][r] = p3;
            l_part[r] += (p0 + p1) + (p2 + p3);
        }

        // P -> LDS (truncating pack; wave-private, no barrier needed)
#pragma unroll
        for (int ct = 0; ct < 4; ++ct)
#pragma unroll
            for (int r = 0; r < 4; ++r)
                *swzp(sPw, 4 * g + r, ct * 16 + l15) = f2bf_trunc(sv[ct][r]);

        // O += P V
#pragma unroll
        for (int kk = 0; kk < 2; ++kk) {
            bf16x8 pf = ld8(swzp(sPw, l15, kk * 32 + 8 * g));
#pragma unroll
            for (int dt = 0; dt < 4; ++dt) {
                bf16x8 vf = ld8(swzp(sVc, dt * 16 + l15, kk * 32 + 8 * g));
                oacc[dt] = MFMA(pf, vf, oacc[dt]);
            }
        }

        // write next tile into the other buffer (loads already drained)
        if (more) {
            unsigned short* sKn = &sK[cur ^ 1][0][0];
            unsigned short* sVn = &sVT[cur ^ 1][0][0];
            *reinterpret_cast<bf16x8*>(swzp(sKn, srow, sc16)) = pk0;
            *reinterpret_cast<bf16x8*>(swzp(sKn, srow, sc16 + 8)) = pk1;
            *reinterpret_cast<bf16x8*>(swzp(sVn, srow, sc16)) = pv0;
            *reinterpret_cast<bf16x8*>(swzp(sVn, srow, sc16 + 8)) = pv1;
        }
        __syncthreads();
        cur ^= 1;
    }

    // epilogue: reduce deferred l across the 16-lane row group, store partials
#pragma unroll
    for (int r = 0; r < 4; ++r) {
        float lt = l_part[r];
#pragma unroll
        for (int d_ = 8; d_ >= 1; d_ >>= 1) lt += __shfl_xor(lt, d_, 64);
        int n = n0 + 16 * w + 4 * g + r;
        size_t rowidx = (size_t)s * NB * NN + (size_t)b * NN + n;
#pragma unroll
        for (int dt = 0; dt < 4; ++dt)
            PO[rowidx * DD + dt * 16 + l15] = f2bf(oacc[dt][r]);
        if (l15 == 0) {
            PML[rowidx * 2 + 0] = m_run[r];  // log2-domain
            PML[rowidx * 2 + 1] = lt;
        }
    }
}

// ---------------- kernel 3: combine + output projection + residual ----------------
// grid 2048 (8 blocks/CU): b | n-tile(32 rows) | c-tile(128). Combine total
// work unchanged (smaller n-tile, more blocks).
__global__ __launch_bounds__(256) void out_fused(
    const unsigned short* __restrict__ Wo, const unsigned short* __restrict__ PO,
    const float* __restrict__ PML, const float* __restrict__ bo,
    const float* __restrict__ gamma, const float* __restrict__ x,
    float* __restrict__ out, int S) {
    const int bid = blockIdx.x;
    const int b = bid >> 9;
    const int rest = bid & 511;
    const int n0 = (rest >> 2) * 32;
    const int c0 = (rest & 3) * 128;
    const int t = threadIdx.x;
    const int lane = t & 63, w = t >> 6;
    const int l15 = lane & 15, g = lane >> 4;

    __shared__ unsigned short sATT[32][72];  // [n][d]

    // phase 1: combine KV-split partials (log2-domain m); 8 threads per row
    {
        const int row = t >> 3;        // 0..31
        const int dq = (t & 7) * 8;    // 0..56
        const size_t base = (size_t)b * NN + n0 + row;
        float m = -1e30f;
        for (int s = 0; s < S; ++s)
            m = fmaxf(m, PML[((size_t)s * NB * NN + base) * 2]);
        float acc[8];
#pragma unroll
        for (int j = 0; j < 8; ++j) acc[j] = 0.f;
        float l = 0.f;
        for (int s = 0; s < S; ++s) {
            size_t rowidx = (size_t)s * NB * NN + base;
            float ms = PML[rowidx * 2 + 0];
            float ls = PML[rowidx * 2 + 1];
            float wgt = __builtin_amdgcn_exp2f(ms - m);
            l += wgt * ls;
            bf16x8 a0 = ld8(&PO[rowidx * DD + dq]);
#pragma unroll
            for (int j = 0; j < 8; ++j) acc[j] += wgt * bf2f((unsigned short)a0[j]);
        }
        float inv = 1.f / l;
        bf16x8 o0;
#pragma unroll
        for (int j = 0; j < 8; ++j) o0[j] = (short)f2bf(acc[j] * inv);
        *reinterpret_cast<bf16x8*>(&sATT[row][dq]) = o0;
    }
    __syncthreads();

    // phase 2: out[c, n] = gamma*(Wo . att + bo) + x ; wave w: 32 c x 32 n
    const int cw = c0 + w * 32;
    f32x4 acc2[2][2];
    const f32x4 z = {0.f, 0.f, 0.f, 0.f};
#pragma unroll
    for (int i = 0; i < 2; ++i)
#pragma unroll
        for (int j = 0; j < 2; ++j) acc2[i][j] = z;

#pragma unroll
    for (int kk = 0; kk < 2; ++kk) {
        bf16x8 af[2], bfr[2];
#pragma unroll
        for (int ct = 0; ct < 2; ++ct)
            af[ct] = ld8(&Wo[(cw + ct * 16 + l15) * DD + kk * 32 + 8 * g]);
#pragma unroll
        for (int nt = 0; nt < 2; ++nt)
            bfr[nt] = ld8(&sATT[nt * 16 + l15][kk * 32 + 8 * g]);
#pragma unroll
        for (int ct = 0; ct < 2; ++ct)
#pragma unroll
            for (int nt = 0; nt < 2; ++nt) acc2[ct][nt] = MFMA(af[ct], bfr[nt], acc2[ct][nt]);
    }

    float gm = gamma[0];
#pragma unroll
    for (int ct = 0; ct < 2; ++ct) {
        int c = cw + ct * 16 + 4 * g;
#pragma unroll
        for (int r = 0; r < 4; ++r) {
            float bias = bo[c + r];
#pragma unroll
            for (int nt = 0; nt < 2; ++nt) {
                int n = n0 + nt * 16 + l15;
                size_t idx = ((size_t)b * CH + c + r) * NN + n;
                out[idx] = gm * (acc2[ct][nt][r] + bias) + x[idx];
            }
        }
    }
}

extern "C" void kernel_launch(void* const* d_in, const int* in_sizes, int n_in,
                              void* d_out, int out_size, void* d_ws, size_t ws_size,
                              hipStream_t stream) {
    const float* x = (const float*)d_in[0];
    const float* Wq = (const float*)d_in[1];
    const float* bq = (const float*)d_in[2];
    const float* Wk = (const float*)d_in[3];
    const float* bk = (const float*)d_in[4];
    const float* Wv = (const float*)d_in[5];
    const float* bv = (const float*)d_in[6];
    const float* Wo = (const float*)d_in[7];
    const float* bo = (const float*)d_in[8];
    const float* gamma = (const float*)d_in[9];
    float* out = (float*)d_out;

    char* ws = (char*)d_ws;
    unsigned short* Wq_bf = (unsigned short*)(ws + 0);
    unsigned short* Wk_bf = (unsigned short*)(ws + 65536);
    unsigned short* Wv_bf = (unsigned short*)(ws + 131072);
    unsigned short* Wo_bf = (unsigned short*)(ws + 196608);
    unsigned short* Qb = (unsigned short*)(ws + 262144);
    unsigned short* Kb = (unsigned short*)(ws + 262144 + 2097152);
    unsigned short* VTb = (unsigned short*)(ws + 262144 + 2 * 2097152);
    const size_t po_off = 262144 + 3ull * 2097152;

    // KV-split factor (deterministic: depends only on ws_size). S=8 measured
    // worse than S=4 (77.7 vs 69.4 us) -> S=4.
    int S = 4;
    while (S > 1 &&
           ws_size < po_off + (size_t)S * (2097152ull + 131072ull))
        S >>= 1;
    unsigned short* PO = (unsigned short*)(ws + po_off);
    float* PML = (float*)(ws + po_off + (size_t)S * 2097152ull);

    hipLaunchKernelGGL(convert_w, dim3(128), dim3(256), 0, stream,
                       Wq, Wk, Wv, Wo, Wq_bf, Wk_bf, Wv_bf, Wo_bf);
    hipLaunchKernelGGL(qkv_kernel, dim3(1024), dim3(256), 0, stream,
                       x, Wq_bf, Wk_bf, Wv_bf, bq, bk, bv, Qb, Kb, VTb);
    hipLaunchKernelGGL(attn_kernel, dim3(256 * S), dim3(256), 0, stream,
                       Qb, Kb, VTb, PO, PML, NN / S);
    hipLaunchKernelGGL(out_fused, dim3(2048), dim3(256), 0, stream,
                       Wo_bf, PO, PML, bo, gamma, x, out, S);
}